// Round 2
// baseline (1077.834 us; speedup 1.0000x reference)
//
#include <hip/hip_runtime.h>
#include <hip/hip_bf16.h>
#include <stdint.h>

#define NRAYS 1048576
#define INFV  1e9f
#define TBIG  1e30f

typedef short short8 __attribute__((ext_vector_type(8)));
typedef float f32x4  __attribute__((ext_vector_type(4)));

// ---- d_ws u32 layout ----
#define WS_B0   16
#define FB0     1024   // L0 frags: 4ct*3h*16lane*4 = 768 u32 (quad0 only)
#define FB1     2048   // L1+L2 frags: 12288 u32

#define PKLO(a,b) ((int)(((unsigned)(a) & 0xFFFFu) | ((unsigned)(b) << 16)))
#define PKHI(a,b) ((int)(((unsigned)(a) >> 16) | ((unsigned)(b) & 0xFFFF0000u)))

__device__ __forceinline__ float ldf(const void* p, int i, int fm) {
    if (fm) return ((const float*)p)[i];
    unsigned u = ((const unsigned short*)p)[i];
    return __uint_as_float(u << 16);
}

__device__ __forceinline__ void split3(float f, int& him, int& lo) {
    unsigned u = __float_as_uint(f);
    float r = f - __uint_as_float(u & 0xFFFF0000u);
    unsigned um = __float_as_uint(r);
    float r2 = r - __uint_as_float(um & 0xFFFF0000u);
    unsigned ul = __float_as_uint(r2);
    him = (int)((u >> 16) | (um & 0xFFFF0000u));
    lo  = (int)(ul >> 16);
}

__device__ __forceinline__ unsigned comp16(int h, float f) {
    unsigned u = __float_as_uint(f);
    if (h == 0) return u >> 16;
    float r = f - __uint_as_float(u & 0xFFFF0000u);
    unsigned um = __float_as_uint(r);
    if (h == 1) return um >> 16;
    float r2 = r - __uint_as_float(um & 0xFFFF0000u);
    return __float_as_uint(r2) >> 16;
}

__device__ __forceinline__ float rsum16(float x) {
    int v;
    v = __builtin_amdgcn_update_dpp(0, __float_as_int(x), 0x128, 0xF, 0xF, false); x += __int_as_float(v);
    v = __builtin_amdgcn_update_dpp(0, __float_as_int(x), 0x124, 0xF, 0xF, false); x += __int_as_float(v);
    v = __builtin_amdgcn_update_dpp(0, __float_as_int(x), 0x122, 0xF, 0xF, false); x += __int_as_float(v);
    v = __builtin_amdgcn_update_dpp(0, __float_as_int(x), 0x121, 0xF, 0xF, false); x += __int_as_float(v);
    return x;
}

union I4S8 { int4 i; short8 s; };
__device__ __forceinline__ short8 mk8i(int a, int b, int c, int d) {
    I4S8 u; u.i = make_int4(a, b, c, d); return u.s;
}
__device__ __forceinline__ short8 ld_frag(const unsigned* p) {
    I4S8 u; u.i = *(const int4*)p; return u.s;
}

// wave-local fence: all LDS traffic in this kernel is wave-private, so a
// lgkmcnt drain replaces __syncthreads (no s_barrier coupling of the 2 waves).
#define WSYNC() asm volatile("s_waitcnt lgkmcnt(0)" ::: "memory")

// ---------------- prologue (unchanged — validated) ----------------
__global__ __launch_bounds__(256) void conv_k(
    const void* __restrict__ mmin, const void* __restrict__ mmax,
    const void* __restrict__ masks,
    const void* __restrict__ W0, const void* __restrict__ b0,
    const void* __restrict__ lng, const void* __restrict__ lnb,
    const void* __restrict__ Ws, const void* __restrict__ bs,
    const void* __restrict__ Wc, const void* __restrict__ bc,
    const void* __restrict__ Wd, const void* __restrict__ bd,
    unsigned* __restrict__ ws)
{
    __shared__ int sfm;
    float* wf = (float*)ws;
    const int tid = threadIdx.x;
    if (tid == 0) {
        unsigned w0 = ((const unsigned*)mmin)[0];
        int fm = ((w0 & 0xFFFFu) == 0u) ? 1 : 0;
        const unsigned* mw = (const unsigned*)masks;
        bool sawBf = false, allBin = true, sawF32 = false;
        for (int i = 0; i < 64; ++i) {
            unsigned w = mw[i], lo = w & 0xFFFFu, hi = w >> 16;
            if (lo == 0x3F80u && (hi == 0x3F80u || hi == 0u)) sawBf = true;
            if (w == 0x3F800000u) sawF32 = true;
            if (w > 1u) allBin = false;
        }
        int ms = sawBf ? 2 : (allBin ? 4 : (sawF32 ? 4 : 1));
        ws[8] = (unsigned)fm; ws[9] = (unsigned)ms;
        for (int c = 0; c < 3; ++c) {
            float mn = ldf(mmin, c, fm), mx = ldf(mmax, c, fm);
            float ext = mx - mn;
            wf[c]     = mn - 0.5f * ext;
            wf[3 + c] = 1.0f / (2.0f * ext);
        }
        wf[6] = ldf(bc, 0, fm);
        wf[7] = ldf(bd, 0, fm);
        sfm = fm;
    }
    __syncthreads();
    const int fm = sfm;

    for (int i = tid; i < 64;  i += 256) { wf[16 + i] = ldf(b0, i, fm); wf[464 + i] = ldf(Wc, i, fm); wf[528 + i] = ldf(Wd, i, fm); }
    for (int i = tid; i < 128; i += 256) { wf[80 + i] = ldf(bs, i, fm); wf[208 + i] = ldf(lng, i, fm); wf[336 + i] = ldf(lnb, i, fm); }

    for (int w = tid; w < 768; w += 256) {
        int ct = w / 192, rem = w % 192;
        int h = rem / 64, wi = rem % 64;
        int lane16 = wi >> 2, p = wi & 3;
        int n = ct * 16 + lane16;
        unsigned word = 0;
        #pragma unroll
        for (int half = 0; half < 2; ++half) {
            int k = 2 * p + half;
            float v = 0.f;
            if (k < 3) {
                for (int pp = 0; pp < 8; ++pp) v += ldf(W0, (3 * pp + k) * 64 + n, fm);
            } else if (k < 6) {
                int c3 = k - 3;
                for (int pp = 0; pp < 8; ++pp) v = fmaf((float)((double)pp / 7.0), ldf(W0, (3 * pp + c3) * 64 + n, fm), v);
            }
            word |= comp16(h, v) << (16 * half);
        }
        ws[FB0 + ((ct * 3 + h) * 16 + lane16) * 4 + p] = word;
    }

    for (int w = tid; w < 12288; w += 256) {
        int li = w / 6144, inner = w % 6144;
        int t = inner >> 8;
        int h = t % 3, ckc = t / 3, kc = ckc & 1, ct = ckc >> 1;
        int wi = inner & 255, lane = wi >> 2, p = wi & 3;
        int qq = lane >> 4, cc = lane & 15;
        int n = ct * 16 + cc;
        int k0 = kc * 32 + qq * 8 + 2 * p;
        float f0 = ldf(Ws, li * 4096 + k0 * 64 + n, fm);
        float f1 = ldf(Ws, li * 4096 + (k0 + 1) * 64 + n, fm);
        ws[FB1 + w] = comp16(h, f0) | (comp16(h, f1) << 16);
    }
}

// ---------------- main: 2 waves/block, 64 rays/wave, fully wave-private LDS.
// Per-wave LDS = 8192 B -> 10 blocks/CU -> 20 waves/CU (5/SIMD) vs prev 16.
// All biases/gains read from global (L1-resident table) or hoisted to regs. ----------------
#define ST1_S 34
#define ST2_S 34

__global__ __launch_bounds__(128, 5) void nbvh_main(
    const void* __restrict__ orig_p, const void* __restrict__ vec_p,
    const void* __restrict__ masks_p, const void* __restrict__ t1_p,
    const void* __restrict__ t2_p, const unsigned* __restrict__ wsu,
    void* __restrict__ out_p)
{
    __shared__ __align__(16) unsigned sT1[2][16][ST1_S];  // 2×2176 B
    __shared__ __align__(16) unsigned sT2[2][16][ST2_S];  // 2×2176 B
    __shared__ float sOV[2][6][64];    // 2×1536 B
    __shared__ float sT1m[2][4][64];   // 2×1024 B
    __shared__ float sT2g[2][4][64];   // 2×1024 B
    __shared__ float sDf[2][64];       // 2×256 B   => total 16384 B

    const float* wf = (const float*)wsu;
    const int fm = (int)wsu[8];
    const int ms = (int)wsu[9];
    const float bcv = wf[6], bdv = wf[7];

    const int tid = threadIdx.x;
    const int Wv  = tid >> 6;          // wave id in block
    const int L   = tid & 63;          // lane
    const int q = L >> 4, c = L & 15;
    const int ray = blockIdx.x * 128 + tid;

    unsigned (&T1)[16][ST1_S] = sT1[Wv];
    unsigned (&T2)[16][ST2_S] = sT2[Wv];
    float (&OV)[6][64]  = sOV[Wv];
    float (&T1m)[4][64] = sT1m[Wv];
    float (&T2g)[4][64] = sT2g[Wv];
    float (&Df)[64]     = sDf[Wv];

    {
        const float mn0 = wf[0], mn1 = wf[1], mn2 = wf[2];
        const float is0 = wf[3], is1 = wf[4], is2 = wf[5];
        const float o0 = ldf(orig_p, 3*ray+0, fm), o1 = ldf(orig_p, 3*ray+1, fm), o2 = ldf(orig_p, 3*ray+2, fm);
        const float v0 = ldf(vec_p,  3*ray+0, fm), v1 = ldf(vec_p,  3*ray+1, fm), v2 = ldf(vec_p,  3*ray+2, fm);
        OV[0][L] = (o0 - mn0) * is0;  OV[1][L] = (o1 - mn1) * is1;  OV[2][L] = (o2 - mn2) * is2;
        OV[3][L] = v0 * is0;          OV[4][L] = v1 * is1;          OV[5][L] = v2 * is2;
        #pragma unroll
        for (int it = 0; it < 4; ++it) {
            const int gi = it * NRAYS + ray;
            bool mk;
            if      (ms == 1) mk = ((const uint8_t*) masks_p)[gi] != 0;
            else if (ms == 2) mk = ((const uint16_t*)masks_p)[gi] != 0;
            else              mk = ((const unsigned*) masks_p)[gi] != 0;
            T1m[it][L] = mk ? ldf(t1_p, gi, fm) : TBIG;   // masked -> dv ~1e30, never selected
            T2g[it][L] = ldf(t2_p, gi, fm);
        }
        Df[L] = INFV;
    }
    WSYNC();

    // loop-invariant per-lane weights (hoisted; L1-hot table)
    float b0r[4], wcr[4], wdr[4];
    #pragma unroll
    for (int ct = 0; ct < 4; ++ct) {
        b0r[ct] = wf[16  + ct * 16 + c];
        wcr[ct] = wf[464 + ct * 16 + c];
        wdr[ct] = wf[528 + ct * 16 + c];
    }

    #pragma unroll 1
    for (int rt = 0; rt < 4; ++rt) {
        #pragma unroll 1
        for (int ip = 0; ip < 2; ++ip) {
            f32x4 acc[2][4];
            short8 Ah[2][2], Am[2][2], Al[2][2];   // [itl][kc]

            // ---------- Layer 0: A from recomputed x (k=6 collapsed) ----------
            {
                short8 Xh[2], Xm[2], Xl[2];
                #pragma unroll
                for (int itl = 0; itl < 2; ++itl) {
                    const int it = ip * 2 + itl;
                    const int row = rt * 16 + c;
                    const float t1v = T1m[it][row];
                    const float dtv = T2g[it][row] - t1v;
                    float x[6];
                    #pragma unroll
                    for (int j = 0; j < 3; ++j) {
                        float ov = OV[j][row], vv = OV[3 + j][row];
                        x[j]     = fmaf(vv, t1v, ov);
                        x[3 + j] = vv * dtv;
                    }
                    int him[6], lo[6];
                    #pragma unroll
                    for (int j = 0; j < 6; ++j) split3(q == 0 ? x[j] : 0.f, him[j], lo[j]);
                    Xh[itl] = mk8i(PKLO(him[0],him[1]), PKLO(him[2],him[3]), PKLO(him[4],him[5]), 0);
                    Xm[itl] = mk8i(PKHI(him[0],him[1]), PKHI(him[2],him[3]), PKHI(him[4],him[5]), 0);
                    Xl[itl] = mk8i(PKLO(lo[0], lo[1]),  PKLO(lo[2], lo[3]),  PKLO(lo[4], lo[5]),  0);
                }
                #pragma unroll
                for (int itl = 0; itl < 2; ++itl)
                    #pragma unroll
                    for (int ct = 0; ct < 4; ++ct) {
                        float b = b0r[ct];
                        f32x4 a; a[0]=a[1]=a[2]=a[3]=b; acc[itl][ct]=a;
                    }
                #pragma unroll
                for (int ct = 0; ct < 4; ++ct) {
                    short8 Bh = (q==0) ? ld_frag(wsu + FB0 + ((ct*3+0)*16 + c)*4) : mk8i(0,0,0,0);
                    short8 Bm = (q==0) ? ld_frag(wsu + FB0 + ((ct*3+1)*16 + c)*4) : mk8i(0,0,0,0);
                    short8 Bl = (q==0) ? ld_frag(wsu + FB0 + ((ct*3+2)*16 + c)*4) : mk8i(0,0,0,0);
                    #pragma unroll
                    for (int itl = 0; itl < 2; ++itl) {
                        acc[itl][ct] = __builtin_amdgcn_mfma_f32_16x16x32_bf16(Xh[itl], Bh, acc[itl][ct], 0,0,0);
                        acc[itl][ct] = __builtin_amdgcn_mfma_f32_16x16x32_bf16(Xh[itl], Bm, acc[itl][ct], 0,0,0);
                        acc[itl][ct] = __builtin_amdgcn_mfma_f32_16x16x32_bf16(Xm[itl], Bh, acc[itl][ct], 0,0,0);
                        acc[itl][ct] = __builtin_amdgcn_mfma_f32_16x16x32_bf16(Xm[itl], Bm, acc[itl][ct], 0,0,0);
                        acc[itl][ct] = __builtin_amdgcn_mfma_f32_16x16x32_bf16(Xh[itl], Bl, acc[itl][ct], 0,0,0);
                        acc[itl][ct] = __builtin_amdgcn_mfma_f32_16x16x32_bf16(Xl[itl], Bh, acc[itl][ct], 0,0,0);
                    }
                }
            }

            // ---------- layers: LN -> half-pass stage -> build A; then matmul ----------
            #pragma unroll 1
            for (int layer = 0; layer < 2; ++layer) {
                const unsigned* fb = wsu + FB1 + layer * 6144;
                const int bo = 80 + layer * 64, go = 208 + layer * 64, ho = 336 + layer * 64;

                // per-layer weights into regs, issued early (hidden under LN math)
                float gvr[4], hvr[4], bvr[4];
                #pragma unroll
                for (int ct = 0; ct < 4; ++ct) {
                    gvr[ct] = wf[go + ct * 16 + c];
                    hvr[ct] = wf[ho + ct * 16 + c];
                    bvr[ct] = wf[bo + ct * 16 + c];
                }

                #pragma unroll
                for (int itl = 0; itl < 2; ++itl) {
                    WSYNC();   // previous itl's A-build reads done
                    float z[4][4];
                    #pragma unroll
                    for (int ct = 0; ct < 4; ++ct)
                        #pragma unroll
                        for (int e = 0; e < 4; ++e) z[ct][e] = fmaxf(acc[itl][ct][e], 0.f);
                    float mu[4], rs[4];
                    #pragma unroll
                    for (int e = 0; e < 4; ++e) {
                        float s  = z[0][e] + z[1][e] + z[2][e] + z[3][e];
                        float s2 = fmaf(z[0][e], z[0][e], fmaf(z[1][e], z[1][e],
                                   fmaf(z[2][e], z[2][e], z[3][e] * z[3][e])));
                        s  = rsum16(s);    // two independent DPP chains interleave
                        s2 = rsum16(s2);
                        mu[e] = s * (1.0f / 64.0f);
                        float var = fmaf(-mu[e], mu[e], s2 * (1.0f / 64.0f));
                        rs[e] = rsqrtf(var + 1e-5f);
                    }
                    int him[4][4], lov[4][4];
                    #pragma unroll
                    for (int ct = 0; ct < 4; ++ct) {
                        const float gv = gvr[ct];
                        const float hv = hvr[ct];
                        #pragma unroll
                        for (int e = 0; e < 4; ++e) {
                            float y = fmaf((z[ct][e] - mu[e]) * rs[e], gv, hv);
                            split3(y, him[ct][e], lov[ct][e]);
                        }
                    }
                    // ---- pass 0: him for chans 0..31 (ct=0,1) + all lo parts ----
                    #pragma unroll
                    for (int e = 0; e < 4; ++e) {
                        const int row = q * 4 + e;
                        T1[row][c]      = (unsigned)him[0][e];
                        T1[row][c + 16] = (unsigned)him[1][e];
                        T2[row][c]      = (unsigned)PKLO(lov[0][e], lov[2][e]);
                        T2[row][c + 16] = (unsigned)PKLO(lov[1][e], lov[3][e]);
                    }
                    WSYNC();   // stores visible (wave-local)
                    const int4 t01 = *(const int4*)&T2[c][q*8];
                    const int4 t23 = *(const int4*)&T2[c][q*8 + 4];
                    {   // kc = 0 frags
                        const int4 w01 = *(const int4*)&T1[c][q*8];
                        const int4 w23 = *(const int4*)&T1[c][q*8 + 4];
                        Ah[itl][0] = mk8i(PKLO(w01.x,w01.y), PKLO(w01.z,w01.w), PKLO(w23.x,w23.y), PKLO(w23.z,w23.w));
                        Am[itl][0] = mk8i(PKHI(w01.x,w01.y), PKHI(w01.z,w01.w), PKHI(w23.x,w23.y), PKHI(w23.z,w23.w));
                        Al[itl][0] = mk8i(PKLO(t01.x,t01.y), PKLO(t01.z,t01.w), PKLO(t23.x,t23.y), PKLO(t23.z,t23.w));
                    }
                    WSYNC();   // kc=0 reads done before overwrite
                    // ---- pass 1: him for chans 32..63 (ct=2,3) ----
                    #pragma unroll
                    for (int e = 0; e < 4; ++e) {
                        const int row = q * 4 + e;
                        T1[row][c]      = (unsigned)him[2][e];
                        T1[row][c + 16] = (unsigned)him[3][e];
                    }
                    WSYNC();   // stores visible
                    {   // kc = 1 frags
                        const int4 w01 = *(const int4*)&T1[c][q*8];
                        const int4 w23 = *(const int4*)&T1[c][q*8 + 4];
                        Ah[itl][1] = mk8i(PKLO(w01.x,w01.y), PKLO(w01.z,w01.w), PKLO(w23.x,w23.y), PKLO(w23.z,w23.w));
                        Am[itl][1] = mk8i(PKHI(w01.x,w01.y), PKHI(w01.z,w01.w), PKHI(w23.x,w23.y), PKHI(w23.z,w23.w));
                        Al[itl][1] = mk8i(PKHI(t01.x,t01.y), PKHI(t01.z,t01.w), PKHI(t23.x,t23.y), PKHI(t23.z,t23.w));
                    }
                }

                #pragma unroll
                for (int itl = 0; itl < 2; ++itl)
                    #pragma unroll
                    for (int ct = 0; ct < 4; ++ct) {
                        float b = bvr[ct];
                        f32x4 a; a[0]=a[1]=a[2]=a[3]=b; acc[itl][ct]=a;
                    }
                #pragma unroll
                for (int kc = 0; kc < 2; ++kc) {
                    #pragma unroll
                    for (int ct = 0; ct < 4; ++ct) {
                        short8 Bh = ld_frag(fb + (((ct*2+kc)*3 + 0) << 8) + (L << 2));
                        short8 Bm = ld_frag(fb + (((ct*2+kc)*3 + 1) << 8) + (L << 2));
                        short8 Bl = ld_frag(fb + (((ct*2+kc)*3 + 2) << 8) + (L << 2));
                        #pragma unroll
                        for (int itl = 0; itl < 2; ++itl) {
                            acc[itl][ct] = __builtin_amdgcn_mfma_f32_16x16x32_bf16(Ah[itl][kc], Bh, acc[itl][ct], 0,0,0);
                            acc[itl][ct] = __builtin_amdgcn_mfma_f32_16x16x32_bf16(Ah[itl][kc], Bm, acc[itl][ct], 0,0,0);
                            acc[itl][ct] = __builtin_amdgcn_mfma_f32_16x16x32_bf16(Am[itl][kc], Bh, acc[itl][ct], 0,0,0);
                            acc[itl][ct] = __builtin_amdgcn_mfma_f32_16x16x32_bf16(Am[itl][kc], Bm, acc[itl][ct], 0,0,0);
                            acc[itl][ct] = __builtin_amdgcn_mfma_f32_16x16x32_bf16(Ah[itl][kc], Bl, acc[itl][ct], 0,0,0);
                            acc[itl][ct] = __builtin_amdgcn_mfma_f32_16x16x32_bf16(Al[itl][kc], Bh, acc[itl][ct], 0,0,0);
                        }
                    }
                }
            }

            // ---------- heads + dist update (C/D layout) ----------
            {
                #pragma unroll
                for (int e = 0; e < 4; ++e) {
                    const int idx = rt * 16 + q * 4 + e;
                    float d = Df[idx];
                    #pragma unroll
                    for (int itl = 0; itl < 2; ++itl) {
                        const int it = ip * 2 + itl;
                        float cp = 0.f, dp = 0.f;
                        #pragma unroll
                        for (int ct = 0; ct < 4; ++ct) {
                            float f = fmaxf(acc[itl][ct][e], 0.f);
                            cp = fmaf(f, wcr[ct], cp);
                            dp = fmaf(f, wdr[ct], dp);
                        }
                        cp = rsum16(cp); dp = rsum16(dp);
                        float cls = cp + bcv;
                        float dv  = dp + bdv + T1m[it][idx];   // masked -> +1e30
                        if (cls > 0.f && dv < d) d = dv;
                    }
                    if (c == 0) Df[idx] = d;
                }
            }
        }
    }

    WSYNC();
    float d = Df[L];
    if (d == INFV) d = 0.f;
    const float hit = (d > 0.f) ? 1.f : 0.f;
    if (fm) {
        ((float*)out_p)[ray]         = hit;
        ((float*)out_p)[NRAYS + ray] = d;
    } else {
        __hip_bfloat16* o = (__hip_bfloat16*)out_p;
        o[ray]         = __float2bfloat16(hit);
        o[NRAYS + ray] = __float2bfloat16(d);
    }
}

extern "C" void kernel_launch(void* const* d_in, const int* in_sizes, int n_in,
                              void* d_out, int out_size, void* d_ws, size_t ws_size,
                              hipStream_t stream) {
    (void)in_sizes; (void)n_in; (void)ws_size; (void)out_size;
    unsigned* ws = (unsigned*)d_ws;
    conv_k<<<1, 256, 0, stream>>>(
        d_in[6], d_in[7], d_in[2],
        d_in[8], d_in[9], d_in[10], d_in[11],
        d_in[12], d_in[13], d_in[14], d_in[15],
        d_in[16], d_in[17], ws);
    nbvh_main<<<NRAYS / 128, 128, 0, stream>>>(
        d_in[0], d_in[1], d_in[2], d_in[4], d_in[5], ws, d_out);
}

// Round 3
// 836.337 us; speedup vs baseline: 1.2888x; 1.2888x over previous
//
#include <hip/hip_runtime.h>
#include <hip/hip_bf16.h>
#include <stdint.h>

#define NRAYS 1048576
#define INFV  1e9f
#define TBIG  1e30f

typedef short short8 __attribute__((ext_vector_type(8)));
typedef float f32x4  __attribute__((ext_vector_type(4)));

// ---- d_ws u32 layout ----
#define WS_B0   16
#define FB0     1024   // L0 frags: 4ct*3h*16lane*4 = 768 u32 (quad0 only)
#define FB1     2048   // L1+L2 frags: 12288 u32

#define PKLO(a,b) ((int)(((unsigned)(a) & 0xFFFFu) | ((unsigned)(b) << 16)))
#define PKHI(a,b) ((int)(((unsigned)(a) >> 16) | ((unsigned)(b) & 0xFFFF0000u)))

__device__ __forceinline__ float ldf(const void* p, int i, int fm) {
    if (fm) return ((const float*)p)[i];
    unsigned u = ((const unsigned short*)p)[i];
    return __uint_as_float(u << 16);
}

__device__ __forceinline__ void split3(float f, int& him, int& lo) {
    unsigned u = __float_as_uint(f);
    float r = f - __uint_as_float(u & 0xFFFF0000u);
    unsigned um = __float_as_uint(r);
    float r2 = r - __uint_as_float(um & 0xFFFF0000u);
    unsigned ul = __float_as_uint(r2);
    him = (int)((u >> 16) | (um & 0xFFFF0000u));
    lo  = (int)(ul >> 16);
}

__device__ __forceinline__ unsigned comp16(int h, float f) {
    unsigned u = __float_as_uint(f);
    if (h == 0) return u >> 16;
    float r = f - __uint_as_float(u & 0xFFFF0000u);
    unsigned um = __float_as_uint(r);
    if (h == 1) return um >> 16;
    float r2 = r - __uint_as_float(um & 0xFFFF0000u);
    return __float_as_uint(r2) >> 16;
}

__device__ __forceinline__ float rsum16(float x) {
    int v;
    v = __builtin_amdgcn_update_dpp(0, __float_as_int(x), 0x128, 0xF, 0xF, false); x += __int_as_float(v);
    v = __builtin_amdgcn_update_dpp(0, __float_as_int(x), 0x124, 0xF, 0xF, false); x += __int_as_float(v);
    v = __builtin_amdgcn_update_dpp(0, __float_as_int(x), 0x122, 0xF, 0xF, false); x += __int_as_float(v);
    v = __builtin_amdgcn_update_dpp(0, __float_as_int(x), 0x121, 0xF, 0xF, false); x += __int_as_float(v);
    return x;
}

union I4S8 { int4 i; short8 s; };
__device__ __forceinline__ short8 mk8i(int a, int b, int c, int d) {
    I4S8 u; u.i = make_int4(a, b, c, d); return u.s;
}
__device__ __forceinline__ short8 ld_frag(const unsigned* p) {
    I4S8 u; u.i = *(const int4*)p; return u.s;
}

// wave-local fence: all LDS traffic in this kernel is wave-private, so a
// lgkmcnt drain replaces __syncthreads (no s_barrier coupling of the 2 waves).
#define WSYNC() asm volatile("s_waitcnt lgkmcnt(0)" ::: "memory")

// ---------------- prologue (unchanged — validated) ----------------
__global__ __launch_bounds__(256) void conv_k(
    const void* __restrict__ mmin, const void* __restrict__ mmax,
    const void* __restrict__ masks,
    const void* __restrict__ W0, const void* __restrict__ b0,
    const void* __restrict__ lng, const void* __restrict__ lnb,
    const void* __restrict__ Ws, const void* __restrict__ bs,
    const void* __restrict__ Wc, const void* __restrict__ bc,
    const void* __restrict__ Wd, const void* __restrict__ bd,
    unsigned* __restrict__ ws)
{
    __shared__ int sfm;
    float* wf = (float*)ws;
    const int tid = threadIdx.x;
    if (tid == 0) {
        unsigned w0 = ((const unsigned*)mmin)[0];
        int fm = ((w0 & 0xFFFFu) == 0u) ? 1 : 0;
        const unsigned* mw = (const unsigned*)masks;
        bool sawBf = false, allBin = true, sawF32 = false;
        for (int i = 0; i < 64; ++i) {
            unsigned w = mw[i], lo = w & 0xFFFFu, hi = w >> 16;
            if (lo == 0x3F80u && (hi == 0x3F80u || hi == 0u)) sawBf = true;
            if (w == 0x3F800000u) sawF32 = true;
            if (w > 1u) allBin = false;
        }
        int ms = sawBf ? 2 : (allBin ? 4 : (sawF32 ? 4 : 1));
        ws[8] = (unsigned)fm; ws[9] = (unsigned)ms;
        for (int c = 0; c < 3; ++c) {
            float mn = ldf(mmin, c, fm), mx = ldf(mmax, c, fm);
            float ext = mx - mn;
            wf[c]     = mn - 0.5f * ext;
            wf[3 + c] = 1.0f / (2.0f * ext);
        }
        wf[6] = ldf(bc, 0, fm);
        wf[7] = ldf(bd, 0, fm);
        sfm = fm;
    }
    __syncthreads();
    const int fm = sfm;

    for (int i = tid; i < 64;  i += 256) { wf[16 + i] = ldf(b0, i, fm); wf[464 + i] = ldf(Wc, i, fm); wf[528 + i] = ldf(Wd, i, fm); }
    for (int i = tid; i < 128; i += 256) { wf[80 + i] = ldf(bs, i, fm); wf[208 + i] = ldf(lng, i, fm); wf[336 + i] = ldf(lnb, i, fm); }

    for (int w = tid; w < 768; w += 256) {
        int ct = w / 192, rem = w % 192;
        int h = rem / 64, wi = rem % 64;
        int lane16 = wi >> 2, p = wi & 3;
        int n = ct * 16 + lane16;
        unsigned word = 0;
        #pragma unroll
        for (int half = 0; half < 2; ++half) {
            int k = 2 * p + half;
            float v = 0.f;
            if (k < 3) {
                for (int pp = 0; pp < 8; ++pp) v += ldf(W0, (3 * pp + k) * 64 + n, fm);
            } else if (k < 6) {
                int c3 = k - 3;
                for (int pp = 0; pp < 8; ++pp) v = fmaf((float)((double)pp / 7.0), ldf(W0, (3 * pp + c3) * 64 + n, fm), v);
            }
            word |= comp16(h, v) << (16 * half);
        }
        ws[FB0 + ((ct * 3 + h) * 16 + lane16) * 4 + p] = word;
    }

    for (int w = tid; w < 12288; w += 256) {
        int li = w / 6144, inner = w % 6144;
        int t = inner >> 8;
        int h = t % 3, ckc = t / 3, kc = ckc & 1, ct = ckc >> 1;
        int wi = inner & 255, lane = wi >> 2, p = wi & 3;
        int qq = lane >> 4, cc = lane & 15;
        int n = ct * 16 + cc;
        int k0 = kc * 32 + qq * 8 + 2 * p;
        float f0 = ldf(Ws, li * 4096 + k0 * 64 + n, fm);
        float f1 = ldf(Ws, li * 4096 + (k0 + 1) * 64 + n, fm);
        ws[FB1 + w] = comp16(h, f0) | (comp16(h, f1) << 16);
    }
}

// ---------------- main: 2 waves/block, 64 rays/wave, fully wave-private LDS.
// Per-wave LDS = 8192 B -> 10 blocks/CU -> 20 waves/CU (5/SIMD).
// launch_bounds(128,4): VGPR cap 128 — R2's (128,5) squeezed to 48 and spilled
// (793 MB scratch writes); the kernel needs ~90 regs live. ----------------
#define ST1_S 34
#define ST2_S 34

__global__ __launch_bounds__(128, 4) void nbvh_main(
    const void* __restrict__ orig_p, const void* __restrict__ vec_p,
    const void* __restrict__ masks_p, const void* __restrict__ t1_p,
    const void* __restrict__ t2_p, const unsigned* __restrict__ wsu,
    void* __restrict__ out_p)
{
    __shared__ __align__(16) unsigned sT1[2][16][ST1_S];  // 2×2176 B
    __shared__ __align__(16) unsigned sT2[2][16][ST2_S];  // 2×2176 B
    __shared__ float sOV[2][6][64];    // 2×1536 B
    __shared__ float sT1m[2][4][64];   // 2×1024 B
    __shared__ float sT2g[2][4][64];   // 2×1024 B
    __shared__ float sDf[2][64];       // 2×256 B   => total 16384 B

    const float* wf = (const float*)wsu;
    const int fm = (int)wsu[8];
    const int ms = (int)wsu[9];
    const float bcv = wf[6], bdv = wf[7];

    const int tid = threadIdx.x;
    const int Wv  = tid >> 6;          // wave id in block
    const int L   = tid & 63;          // lane
    const int q = L >> 4, c = L & 15;
    const int ray = blockIdx.x * 128 + tid;

    unsigned (&T1)[16][ST1_S] = sT1[Wv];
    unsigned (&T2)[16][ST2_S] = sT2[Wv];
    float (&OV)[6][64]  = sOV[Wv];
    float (&T1m)[4][64] = sT1m[Wv];
    float (&T2g)[4][64] = sT2g[Wv];
    float (&Df)[64]     = sDf[Wv];

    {
        const float mn0 = wf[0], mn1 = wf[1], mn2 = wf[2];
        const float is0 = wf[3], is1 = wf[4], is2 = wf[5];
        const float o0 = ldf(orig_p, 3*ray+0, fm), o1 = ldf(orig_p, 3*ray+1, fm), o2 = ldf(orig_p, 3*ray+2, fm);
        const float v0 = ldf(vec_p,  3*ray+0, fm), v1 = ldf(vec_p,  3*ray+1, fm), v2 = ldf(vec_p,  3*ray+2, fm);
        OV[0][L] = (o0 - mn0) * is0;  OV[1][L] = (o1 - mn1) * is1;  OV[2][L] = (o2 - mn2) * is2;
        OV[3][L] = v0 * is0;          OV[4][L] = v1 * is1;          OV[5][L] = v2 * is2;
        #pragma unroll
        for (int it = 0; it < 4; ++it) {
            const int gi = it * NRAYS + ray;
            bool mk;
            if      (ms == 1) mk = ((const uint8_t*) masks_p)[gi] != 0;
            else if (ms == 2) mk = ((const uint16_t*)masks_p)[gi] != 0;
            else              mk = ((const unsigned*) masks_p)[gi] != 0;
            T1m[it][L] = mk ? ldf(t1_p, gi, fm) : TBIG;   // masked -> dv ~1e30, never selected
            T2g[it][L] = ldf(t2_p, gi, fm);
        }
        Df[L] = INFV;
    }
    WSYNC();

    // loop-invariant per-lane weights (hoisted; L1-hot table)
    float b0r[4], wcr[4], wdr[4];
    #pragma unroll
    for (int ct = 0; ct < 4; ++ct) {
        b0r[ct] = wf[16  + ct * 16 + c];
        wcr[ct] = wf[464 + ct * 16 + c];
        wdr[ct] = wf[528 + ct * 16 + c];
    }

    #pragma unroll 1
    for (int rt = 0; rt < 4; ++rt) {
        #pragma unroll 1
        for (int ip = 0; ip < 2; ++ip) {
            f32x4 acc[2][4];
            short8 Ah[2][2], Am[2][2], Al[2][2];   // [itl][kc]

            // ---------- Layer 0: A from recomputed x (k=6 collapsed) ----------
            {
                short8 Xh[2], Xm[2], Xl[2];
                #pragma unroll
                for (int itl = 0; itl < 2; ++itl) {
                    const int it = ip * 2 + itl;
                    const int row = rt * 16 + c;
                    const float t1v = T1m[it][row];
                    const float dtv = T2g[it][row] - t1v;
                    float x[6];
                    #pragma unroll
                    for (int j = 0; j < 3; ++j) {
                        float ov = OV[j][row], vv = OV[3 + j][row];
                        x[j]     = fmaf(vv, t1v, ov);
                        x[3 + j] = vv * dtv;
                    }
                    int him[6], lo[6];
                    #pragma unroll
                    for (int j = 0; j < 6; ++j) split3(q == 0 ? x[j] : 0.f, him[j], lo[j]);
                    Xh[itl] = mk8i(PKLO(him[0],him[1]), PKLO(him[2],him[3]), PKLO(him[4],him[5]), 0);
                    Xm[itl] = mk8i(PKHI(him[0],him[1]), PKHI(him[2],him[3]), PKHI(him[4],him[5]), 0);
                    Xl[itl] = mk8i(PKLO(lo[0], lo[1]),  PKLO(lo[2], lo[3]),  PKLO(lo[4], lo[5]),  0);
                }
                #pragma unroll
                for (int itl = 0; itl < 2; ++itl)
                    #pragma unroll
                    for (int ct = 0; ct < 4; ++ct) {
                        float b = b0r[ct];
                        f32x4 a; a[0]=a[1]=a[2]=a[3]=b; acc[itl][ct]=a;
                    }
                #pragma unroll
                for (int ct = 0; ct < 4; ++ct) {
                    short8 Bh = (q==0) ? ld_frag(wsu + FB0 + ((ct*3+0)*16 + c)*4) : mk8i(0,0,0,0);
                    short8 Bm = (q==0) ? ld_frag(wsu + FB0 + ((ct*3+1)*16 + c)*4) : mk8i(0,0,0,0);
                    short8 Bl = (q==0) ? ld_frag(wsu + FB0 + ((ct*3+2)*16 + c)*4) : mk8i(0,0,0,0);
                    #pragma unroll
                    for (int itl = 0; itl < 2; ++itl) {
                        acc[itl][ct] = __builtin_amdgcn_mfma_f32_16x16x32_bf16(Xh[itl], Bh, acc[itl][ct], 0,0,0);
                        acc[itl][ct] = __builtin_amdgcn_mfma_f32_16x16x32_bf16(Xh[itl], Bm, acc[itl][ct], 0,0,0);
                        acc[itl][ct] = __builtin_amdgcn_mfma_f32_16x16x32_bf16(Xm[itl], Bh, acc[itl][ct], 0,0,0);
                        acc[itl][ct] = __builtin_amdgcn_mfma_f32_16x16x32_bf16(Xm[itl], Bm, acc[itl][ct], 0,0,0);
                        acc[itl][ct] = __builtin_amdgcn_mfma_f32_16x16x32_bf16(Xh[itl], Bl, acc[itl][ct], 0,0,0);
                        acc[itl][ct] = __builtin_amdgcn_mfma_f32_16x16x32_bf16(Xl[itl], Bh, acc[itl][ct], 0,0,0);
                    }
                }
            }

            // ---------- layers: LN -> half-pass stage -> build A; then matmul ----------
            #pragma unroll 1
            for (int layer = 0; layer < 2; ++layer) {
                const unsigned* fb = wsu + FB1 + layer * 6144;
                const int bo = 80 + layer * 64, go = 208 + layer * 64, ho = 336 + layer * 64;

                // per-layer weights into regs, issued early (hidden under LN math)
                float gvr[4], hvr[4], bvr[4];
                #pragma unroll
                for (int ct = 0; ct < 4; ++ct) {
                    gvr[ct] = wf[go + ct * 16 + c];
                    hvr[ct] = wf[ho + ct * 16 + c];
                    bvr[ct] = wf[bo + ct * 16 + c];
                }

                #pragma unroll
                for (int itl = 0; itl < 2; ++itl) {
                    WSYNC();   // previous itl's A-build reads done
                    float z[4][4];
                    #pragma unroll
                    for (int ct = 0; ct < 4; ++ct)
                        #pragma unroll
                        for (int e = 0; e < 4; ++e) z[ct][e] = fmaxf(acc[itl][ct][e], 0.f);
                    float mu[4], rs[4];
                    #pragma unroll
                    for (int e = 0; e < 4; ++e) {
                        float s  = z[0][e] + z[1][e] + z[2][e] + z[3][e];
                        float s2 = fmaf(z[0][e], z[0][e], fmaf(z[1][e], z[1][e],
                                   fmaf(z[2][e], z[2][e], z[3][e] * z[3][e])));
                        s  = rsum16(s);    // two independent DPP chains interleave
                        s2 = rsum16(s2);
                        mu[e] = s * (1.0f / 64.0f);
                        float var = fmaf(-mu[e], mu[e], s2 * (1.0f / 64.0f));
                        rs[e] = rsqrtf(var + 1e-5f);
                    }
                    int him[4][4], lov[4][4];
                    #pragma unroll
                    for (int ct = 0; ct < 4; ++ct) {
                        const float gv = gvr[ct];
                        const float hv = hvr[ct];
                        #pragma unroll
                        for (int e = 0; e < 4; ++e) {
                            float y = fmaf((z[ct][e] - mu[e]) * rs[e], gv, hv);
                            split3(y, him[ct][e], lov[ct][e]);
                        }
                    }
                    // ---- pass 0: him for chans 0..31 (ct=0,1) + all lo parts ----
                    #pragma unroll
                    for (int e = 0; e < 4; ++e) {
                        const int row = q * 4 + e;
                        T1[row][c]      = (unsigned)him[0][e];
                        T1[row][c + 16] = (unsigned)him[1][e];
                        T2[row][c]      = (unsigned)PKLO(lov[0][e], lov[2][e]);
                        T2[row][c + 16] = (unsigned)PKLO(lov[1][e], lov[3][e]);
                    }
                    WSYNC();   // stores visible (wave-local)
                    const int4 t01 = *(const int4*)&T2[c][q*8];
                    const int4 t23 = *(const int4*)&T2[c][q*8 + 4];
                    {   // kc = 0 frags
                        const int4 w01 = *(const int4*)&T1[c][q*8];
                        const int4 w23 = *(const int4*)&T1[c][q*8 + 4];
                        Ah[itl][0] = mk8i(PKLO(w01.x,w01.y), PKLO(w01.z,w01.w), PKLO(w23.x,w23.y), PKLO(w23.z,w23.w));
                        Am[itl][0] = mk8i(PKHI(w01.x,w01.y), PKHI(w01.z,w01.w), PKHI(w23.x,w23.y), PKHI(w23.z,w23.w));
                        Al[itl][0] = mk8i(PKLO(t01.x,t01.y), PKLO(t01.z,t01.w), PKLO(t23.x,t23.y), PKLO(t23.z,t23.w));
                    }
                    WSYNC();   // kc=0 reads done before overwrite
                    // ---- pass 1: him for chans 32..63 (ct=2,3) ----
                    #pragma unroll
                    for (int e = 0; e < 4; ++e) {
                        const int row = q * 4 + e;
                        T1[row][c]      = (unsigned)him[2][e];
                        T1[row][c + 16] = (unsigned)him[3][e];
                    }
                    WSYNC();   // stores visible
                    {   // kc = 1 frags
                        const int4 w01 = *(const int4*)&T1[c][q*8];
                        const int4 w23 = *(const int4*)&T1[c][q*8 + 4];
                        Ah[itl][1] = mk8i(PKLO(w01.x,w01.y), PKLO(w01.z,w01.w), PKLO(w23.x,w23.y), PKLO(w23.z,w23.w));
                        Am[itl][1] = mk8i(PKHI(w01.x,w01.y), PKHI(w01.z,w01.w), PKHI(w23.x,w23.y), PKHI(w23.z,w23.w));
                        Al[itl][1] = mk8i(PKHI(t01.x,t01.y), PKHI(t01.z,t01.w), PKHI(t23.x,t23.y), PKHI(t23.z,t23.w));
                    }
                }

                #pragma unroll
                for (int itl = 0; itl < 2; ++itl)
                    #pragma unroll
                    for (int ct = 0; ct < 4; ++ct) {
                        float b = bvr[ct];
                        f32x4 a; a[0]=a[1]=a[2]=a[3]=b; acc[itl][ct]=a;
                    }
                #pragma unroll
                for (int kc = 0; kc < 2; ++kc) {
                    #pragma unroll
                    for (int ct = 0; ct < 4; ++ct) {
                        short8 Bh = ld_frag(fb + (((ct*2+kc)*3 + 0) << 8) + (L << 2));
                        short8 Bm = ld_frag(fb + (((ct*2+kc)*3 + 1) << 8) + (L << 2));
                        short8 Bl = ld_frag(fb + (((ct*2+kc)*3 + 2) << 8) + (L << 2));
                        #pragma unroll
                        for (int itl = 0; itl < 2; ++itl) {
                            acc[itl][ct] = __builtin_amdgcn_mfma_f32_16x16x32_bf16(Ah[itl][kc], Bh, acc[itl][ct], 0,0,0);
                            acc[itl][ct] = __builtin_amdgcn_mfma_f32_16x16x32_bf16(Ah[itl][kc], Bm, acc[itl][ct], 0,0,0);
                            acc[itl][ct] = __builtin_amdgcn_mfma_f32_16x16x32_bf16(Am[itl][kc], Bh, acc[itl][ct], 0,0,0);
                            acc[itl][ct] = __builtin_amdgcn_mfma_f32_16x16x32_bf16(Am[itl][kc], Bm, acc[itl][ct], 0,0,0);
                            acc[itl][ct] = __builtin_amdgcn_mfma_f32_16x16x32_bf16(Ah[itl][kc], Bl, acc[itl][ct], 0,0,0);
                            acc[itl][ct] = __builtin_amdgcn_mfma_f32_16x16x32_bf16(Al[itl][kc], Bh, acc[itl][ct], 0,0,0);
                        }
                    }
                }
            }

            // ---------- heads + dist update (C/D layout) ----------
            {
                #pragma unroll
                for (int e = 0; e < 4; ++e) {
                    const int idx = rt * 16 + q * 4 + e;
                    float d = Df[idx];
                    #pragma unroll
                    for (int itl = 0; itl < 2; ++itl) {
                        const int it = ip * 2 + itl;
                        float cp = 0.f, dp = 0.f;
                        #pragma unroll
                        for (int ct = 0; ct < 4; ++ct) {
                            float f = fmaxf(acc[itl][ct][e], 0.f);
                            cp = fmaf(f, wcr[ct], cp);
                            dp = fmaf(f, wdr[ct], dp);
                        }
                        cp = rsum16(cp); dp = rsum16(dp);
                        float cls = cp + bcv;
                        float dv  = dp + bdv + T1m[it][idx];   // masked -> +1e30
                        if (cls > 0.f && dv < d) d = dv;
                    }
                    if (c == 0) Df[idx] = d;
                }
            }
        }
    }

    WSYNC();
    float d = Df[L];
    if (d == INFV) d = 0.f;
    const float hit = (d > 0.f) ? 1.f : 0.f;
    if (fm) {
        ((float*)out_p)[ray]         = hit;
        ((float*)out_p)[NRAYS + ray] = d;
    } else {
        __hip_bfloat16* o = (__hip_bfloat16*)out_p;
        o[ray]         = __float2bfloat16(hit);
        o[NRAYS + ray] = __float2bfloat16(d);
    }
}

extern "C" void kernel_launch(void* const* d_in, const int* in_sizes, int n_in,
                              void* d_out, int out_size, void* d_ws, size_t ws_size,
                              hipStream_t stream) {
    (void)in_sizes; (void)n_in; (void)ws_size; (void)out_size;
    unsigned* ws = (unsigned*)d_ws;
    conv_k<<<1, 256, 0, stream>>>(
        d_in[6], d_in[7], d_in[2],
        d_in[8], d_in[9], d_in[10], d_in[11],
        d_in[12], d_in[13], d_in[14], d_in[15],
        d_in[16], d_in[17], ws);
    nbvh_main<<<NRAYS / 128, 128, 0, stream>>>(
        d_in[0], d_in[1], d_in[2], d_in[4], d_in[5], ws, d_out);
}

// Round 4
// 711.804 us; speedup vs baseline: 1.5142x; 1.1750x over previous
//
#include <hip/hip_runtime.h>
#include <hip/hip_bf16.h>
#include <stdint.h>

#define NRAYS 1048576
#define INFV  1e9f
#define TBIG  1e30f

typedef short short8 __attribute__((ext_vector_type(8)));
typedef float f32x4  __attribute__((ext_vector_type(4)));

// ---- d_ws u32 layout ----
#define WS_B0   16
#define FB0     1024   // L0 frags: 4ct*3h*16lane*4 = 768 u32 (quad0 only)
#define FB1     2048   // L1+L2 frags: 12288 u32

// legacy 2-op packs (prologue only)
#define PKLO(a,b) ((int)(((unsigned)(a) & 0xFFFFu) | ((unsigned)(b) << 16)))
#define PKHI(a,b) ((int)(((unsigned)(a) >> 16) | ((unsigned)(b) & 0xFFFF0000u)))

// single v_perm_b32 packs (main kernel): sel bytes index {S0:S1}, S1=bytes 0-3
__device__ __forceinline__ int pklo(int a, int b) {   // (a&0xFFFF)|(b<<16)
    return (int)__builtin_amdgcn_perm((unsigned)b, (unsigned)a, 0x05040100u);
}
__device__ __forceinline__ int pkhi(int a, int b) {   // (a>>16)|(b&0xFFFF0000)
    return (int)__builtin_amdgcn_perm((unsigned)b, (unsigned)a, 0x07060302u);
}

__device__ __forceinline__ float ldf(const void* p, int i, int fm) {
    if (fm) return ((const float*)p)[i];
    unsigned u = ((const unsigned short*)p)[i];
    return __uint_as_float(u << 16);
}

// bf16x3 split: him = {m_hi16 | h_in_lo16} (1 perm), lo returned RAW
// (low bf16 lives in bytes 2-3; consumers pack pairs with pkhi).
__device__ __forceinline__ void split3(float f, int& him, int& lo_raw) {
    unsigned u = __float_as_uint(f);
    float r = f - __uint_as_float(u & 0xFFFF0000u);
    unsigned um = __float_as_uint(r);
    float r2 = r - __uint_as_float(um & 0xFFFF0000u);
    him    = pkhi((int)u, (int)um);     // (u>>16)|(um&0xFFFF0000)
    lo_raw = (int)__float_as_uint(r2);
}

__device__ __forceinline__ unsigned comp16(int h, float f) {
    unsigned u = __float_as_uint(f);
    if (h == 0) return u >> 16;
    float r = f - __uint_as_float(u & 0xFFFF0000u);
    unsigned um = __float_as_uint(r);
    if (h == 1) return um >> 16;
    float r2 = r - __uint_as_float(um & 0xFFFF0000u);
    return __float_as_uint(r2) >> 16;
}

__device__ __forceinline__ float rsum16(float x) {
    int v;
    v = __builtin_amdgcn_update_dpp(0, __float_as_int(x), 0x128, 0xF, 0xF, false); x += __int_as_float(v);
    v = __builtin_amdgcn_update_dpp(0, __float_as_int(x), 0x124, 0xF, 0xF, false); x += __int_as_float(v);
    v = __builtin_amdgcn_update_dpp(0, __float_as_int(x), 0x122, 0xF, 0xF, false); x += __int_as_float(v);
    v = __builtin_amdgcn_update_dpp(0, __float_as_int(x), 0x121, 0xF, 0xF, false); x += __int_as_float(v);
    return x;
}

union I4S8 { int4 i; short8 s; };
__device__ __forceinline__ short8 mk8i(int a, int b, int c, int d) {
    I4S8 u; u.i = make_int4(a, b, c, d); return u.s;
}
__device__ __forceinline__ short8 ld_frag(const unsigned* p) {
    I4S8 u; u.i = *(const int4*)p; return u.s;
}

// ---------------- prologue (unchanged — validated) ----------------
__global__ __launch_bounds__(256) void conv_k(
    const void* __restrict__ mmin, const void* __restrict__ mmax,
    const void* __restrict__ masks,
    const void* __restrict__ W0, const void* __restrict__ b0,
    const void* __restrict__ lng, const void* __restrict__ lnb,
    const void* __restrict__ Ws, const void* __restrict__ bs,
    const void* __restrict__ Wc, const void* __restrict__ bc,
    const void* __restrict__ Wd, const void* __restrict__ bd,
    unsigned* __restrict__ ws)
{
    __shared__ int sfm;
    float* wf = (float*)ws;
    const int tid = threadIdx.x;
    if (tid == 0) {
        unsigned w0 = ((const unsigned*)mmin)[0];
        int fm = ((w0 & 0xFFFFu) == 0u) ? 1 : 0;
        const unsigned* mw = (const unsigned*)masks;
        bool sawBf = false, allBin = true, sawF32 = false;
        for (int i = 0; i < 64; ++i) {
            unsigned w = mw[i], lo = w & 0xFFFFu, hi = w >> 16;
            if (lo == 0x3F80u && (hi == 0x3F80u || hi == 0u)) sawBf = true;
            if (w == 0x3F800000u) sawF32 = true;
            if (w > 1u) allBin = false;
        }
        int ms = sawBf ? 2 : (allBin ? 4 : (sawF32 ? 4 : 1));
        ws[8] = (unsigned)fm; ws[9] = (unsigned)ms;
        for (int c = 0; c < 3; ++c) {
            float mn = ldf(mmin, c, fm), mx = ldf(mmax, c, fm);
            float ext = mx - mn;
            wf[c]     = mn - 0.5f * ext;
            wf[3 + c] = 1.0f / (2.0f * ext);
        }
        wf[6] = ldf(bc, 0, fm);
        wf[7] = ldf(bd, 0, fm);
        sfm = fm;
    }
    __syncthreads();
    const int fm = sfm;

    for (int i = tid; i < 64;  i += 256) { wf[16 + i] = ldf(b0, i, fm); wf[464 + i] = ldf(Wc, i, fm); wf[528 + i] = ldf(Wd, i, fm); }
    for (int i = tid; i < 128; i += 256) { wf[80 + i] = ldf(bs, i, fm); wf[208 + i] = ldf(lng, i, fm); wf[336 + i] = ldf(lnb, i, fm); }

    for (int w = tid; w < 768; w += 256) {
        int ct = w / 192, rem = w % 192;
        int h = rem / 64, wi = rem % 64;
        int lane16 = wi >> 2, p = wi & 3;
        int n = ct * 16 + lane16;
        unsigned word = 0;
        #pragma unroll
        for (int half = 0; half < 2; ++half) {
            int k = 2 * p + half;
            float v = 0.f;
            if (k < 3) {
                for (int pp = 0; pp < 8; ++pp) v += ldf(W0, (3 * pp + k) * 64 + n, fm);
            } else if (k < 6) {
                int c3 = k - 3;
                for (int pp = 0; pp < 8; ++pp) v = fmaf((float)((double)pp / 7.0), ldf(W0, (3 * pp + c3) * 64 + n, fm), v);
            }
            word |= comp16(h, v) << (16 * half);
        }
        ws[FB0 + ((ct * 3 + h) * 16 + lane16) * 4 + p] = word;
    }

    for (int w = tid; w < 12288; w += 256) {
        int li = w / 6144, inner = w % 6144;
        int t = inner >> 8;
        int h = t % 3, ckc = t / 3, kc = ckc & 1, ct = ckc >> 1;
        int wi = inner & 255, lane = wi >> 2, p = wi & 3;
        int qq = lane >> 4, cc = lane & 15;
        int n = ct * 16 + cc;
        int k0 = kc * 32 + qq * 8 + 2 * p;
        float f0 = ldf(Ws, li * 4096 + k0 * 64 + n, fm);
        float f1 = ldf(Ws, li * 4096 + (k0 + 1) * 64 + n, fm);
        ws[FB1 + w] = comp16(h, f0) | (comp16(h, f1) << 16);
    }
}

// ---------------- main: R1 structure (proven 709 µs) + v_perm packing + setprio.
// 64 rays/wave, 1-wave blocks, LDS 9984 B -> 16 blocks/CU (4 waves/SIMD).
// (128,·) 2-wave variants spill: unified VGPR file leaves ~64 arch regs at
// 4 waves/EU and this kernel needs weights in LDS, not hoisted regs. ----------------
#define ST1_S 34
#define ST2_S 34

__global__ __launch_bounds__(64, 4) void nbvh_main(
    const void* __restrict__ orig_p, const void* __restrict__ vec_p,
    const void* __restrict__ masks_p, const void* __restrict__ t1_p,
    const void* __restrict__ t2_p, const unsigned* __restrict__ wsu,
    void* __restrict__ out_p)
{
    __shared__ __align__(16) unsigned sT1[16][ST1_S];  // 2176 B (one kc half at a time)
    __shared__ __align__(16) unsigned sT2[16][ST2_S];  // 2176 B (lo parts, both kc packed)
    __shared__ float sOV[6][64];    // pre-normalized o',v' (1536 B)
    __shared__ float sT1m[4][64];   // t1 or 1e30 if masked (1024 B)
    __shared__ float sT2g[4][64];   // t2 (1024 B)
    __shared__ float sB[448];       // b0|bs0|bs1|g1|g2|h1|h2 (1792 B)
    __shared__ float sDf[64];       // 256 B

    const float* wf = (const float*)wsu;
    const int fm = (int)wsu[8];
    const int ms = (int)wsu[9];
    const float bcv = wf[6], bdv = wf[7];

    const int L = threadIdx.x;
    const int q = L >> 4, c = L & 15;
    const int ray = blockIdx.x * 64 + L;

    for (int i = L; i < 448; i += 64) sB[i] = wf[16 + i];

    {
        const float mn0 = wf[0], mn1 = wf[1], mn2 = wf[2];
        const float is0 = wf[3], is1 = wf[4], is2 = wf[5];
        const float o0 = ldf(orig_p, 3*ray+0, fm), o1 = ldf(orig_p, 3*ray+1, fm), o2 = ldf(orig_p, 3*ray+2, fm);
        const float v0 = ldf(vec_p,  3*ray+0, fm), v1 = ldf(vec_p,  3*ray+1, fm), v2 = ldf(vec_p,  3*ray+2, fm);
        sOV[0][L] = (o0 - mn0) * is0;  sOV[1][L] = (o1 - mn1) * is1;  sOV[2][L] = (o2 - mn2) * is2;
        sOV[3][L] = v0 * is0;          sOV[4][L] = v1 * is1;          sOV[5][L] = v2 * is2;
        #pragma unroll
        for (int it = 0; it < 4; ++it) {
            const int gi = it * NRAYS + ray;
            bool mk;
            if      (ms == 1) mk = ((const uint8_t*) masks_p)[gi] != 0;
            else if (ms == 2) mk = ((const uint16_t*)masks_p)[gi] != 0;
            else              mk = ((const unsigned*) masks_p)[gi] != 0;
            sT1m[it][L] = mk ? ldf(t1_p, gi, fm) : TBIG;   // masked -> dv ~1e30, never selected
            sT2g[it][L] = ldf(t2_p, gi, fm);
        }
        sDf[L] = INFV;
    }
    __syncthreads();

    #pragma unroll 1
    for (int rt = 0; rt < 4; ++rt) {
        #pragma unroll 1
        for (int ip = 0; ip < 2; ++ip) {
            f32x4 acc[2][4];
            short8 Ah[2][2], Am[2][2], Al[2][2];   // [itl][kc]

            // ---------- Layer 0: A from recomputed x (k=6 collapsed) ----------
            {
                short8 Xh[2], Xm[2], Xl[2];
                #pragma unroll
                for (int itl = 0; itl < 2; ++itl) {
                    const int it = ip * 2 + itl;
                    const int row = rt * 16 + c;
                    const float t1v = sT1m[it][row];
                    const float dtv = sT2g[it][row] - t1v;
                    float x[6];
                    #pragma unroll
                    for (int j = 0; j < 3; ++j) {
                        float ov = sOV[j][row], vv = sOV[3 + j][row];
                        x[j]     = fmaf(vv, t1v, ov);
                        x[3 + j] = vv * dtv;
                    }
                    int him[6], lo[6];
                    #pragma unroll
                    for (int j = 0; j < 6; ++j) split3(q == 0 ? x[j] : 0.f, him[j], lo[j]);
                    Xh[itl] = mk8i(pklo(him[0],him[1]), pklo(him[2],him[3]), pklo(him[4],him[5]), 0);
                    Xm[itl] = mk8i(pkhi(him[0],him[1]), pkhi(him[2],him[3]), pkhi(him[4],him[5]), 0);
                    // lo[] raw: low bf16 in bytes 2-3 -> pair-pack via pkhi
                    Xl[itl] = mk8i(pkhi(lo[0], lo[1]),  pkhi(lo[2], lo[3]),  pkhi(lo[4], lo[5]),  0);
                }
                #pragma unroll
                for (int itl = 0; itl < 2; ++itl)
                    #pragma unroll
                    for (int ct = 0; ct < 4; ++ct) {
                        float b = sB[ct * 16 + c];
                        f32x4 a; a[0]=a[1]=a[2]=a[3]=b; acc[itl][ct]=a;
                    }
                __builtin_amdgcn_s_setprio(1);
                #pragma unroll
                for (int ct = 0; ct < 4; ++ct) {
                    short8 Bh = (q==0) ? ld_frag(wsu + FB0 + ((ct*3+0)*16 + c)*4) : mk8i(0,0,0,0);
                    short8 Bm = (q==0) ? ld_frag(wsu + FB0 + ((ct*3+1)*16 + c)*4) : mk8i(0,0,0,0);
                    short8 Bl = (q==0) ? ld_frag(wsu + FB0 + ((ct*3+2)*16 + c)*4) : mk8i(0,0,0,0);
                    #pragma unroll
                    for (int itl = 0; itl < 2; ++itl) {
                        acc[itl][ct] = __builtin_amdgcn_mfma_f32_16x16x32_bf16(Xh[itl], Bh, acc[itl][ct], 0,0,0);
                        acc[itl][ct] = __builtin_amdgcn_mfma_f32_16x16x32_bf16(Xh[itl], Bm, acc[itl][ct], 0,0,0);
                        acc[itl][ct] = __builtin_amdgcn_mfma_f32_16x16x32_bf16(Xm[itl], Bh, acc[itl][ct], 0,0,0);
                        acc[itl][ct] = __builtin_amdgcn_mfma_f32_16x16x32_bf16(Xm[itl], Bm, acc[itl][ct], 0,0,0);
                        acc[itl][ct] = __builtin_amdgcn_mfma_f32_16x16x32_bf16(Xh[itl], Bl, acc[itl][ct], 0,0,0);
                        acc[itl][ct] = __builtin_amdgcn_mfma_f32_16x16x32_bf16(Xl[itl], Bh, acc[itl][ct], 0,0,0);
                    }
                }
                __builtin_amdgcn_s_setprio(0);
            }

            // ---------- layers: LN -> half-pass stage -> build A; then matmul ----------
            #pragma unroll 1
            for (int layer = 0; layer < 2; ++layer) {
                const unsigned* fb = wsu + FB1 + layer * 6144;
                const int bo = 64 + layer * 64, go = 192 + layer * 64, ho = 320 + layer * 64;

                #pragma unroll
                for (int itl = 0; itl < 2; ++itl) {
                    __syncthreads();   // previous itl's A-build reads done
                    float z[4][4];
                    #pragma unroll
                    for (int ct = 0; ct < 4; ++ct)
                        #pragma unroll
                        for (int e = 0; e < 4; ++e) z[ct][e] = fmaxf(acc[itl][ct][e], 0.f);
                    float mu[4], rs[4];
                    #pragma unroll
                    for (int e = 0; e < 4; ++e) {
                        float s  = z[0][e] + z[1][e] + z[2][e] + z[3][e];
                        float s2 = fmaf(z[0][e], z[0][e], fmaf(z[1][e], z[1][e],
                                   fmaf(z[2][e], z[2][e], z[3][e] * z[3][e])));
                        s  = rsum16(s);    // two independent DPP chains interleave
                        s2 = rsum16(s2);
                        mu[e] = s * (1.0f / 64.0f);
                        float var = fmaf(-mu[e], mu[e], s2 * (1.0f / 64.0f));
                        rs[e] = rsqrtf(var + 1e-5f);
                    }
                    int him[4][4], lov[4][4];
                    #pragma unroll
                    for (int ct = 0; ct < 4; ++ct) {
                        const float gv = sB[go + ct * 16 + c];
                        const float hv = sB[ho + ct * 16 + c];
                        #pragma unroll
                        for (int e = 0; e < 4; ++e) {
                            float y = fmaf((z[ct][e] - mu[e]) * rs[e], gv, hv);
                            split3(y, him[ct][e], lov[ct][e]);
                        }
                    }
                    // ---- pass 0: him for chans 0..31 (ct=0,1) + all lo parts ----
                    #pragma unroll
                    for (int e = 0; e < 4; ++e) {
                        const int row = q * 4 + e;
                        sT1[row][c]      = (unsigned)him[0][e];
                        sT1[row][c + 16] = (unsigned)him[1][e];
                        // lov raw: pair-pack low bf16s via pkhi
                        sT2[row][c]      = (unsigned)pkhi(lov[0][e], lov[2][e]);
                        sT2[row][c + 16] = (unsigned)pkhi(lov[1][e], lov[3][e]);
                    }
                    __syncthreads();   // stores visible
                    const int4 t01 = *(const int4*)&sT2[c][q*8];
                    const int4 t23 = *(const int4*)&sT2[c][q*8 + 4];
                    {   // kc = 0 frags
                        const int4 w01 = *(const int4*)&sT1[c][q*8];
                        const int4 w23 = *(const int4*)&sT1[c][q*8 + 4];
                        Ah[itl][0] = mk8i(pklo(w01.x,w01.y), pklo(w01.z,w01.w), pklo(w23.x,w23.y), pklo(w23.z,w23.w));
                        Am[itl][0] = mk8i(pkhi(w01.x,w01.y), pkhi(w01.z,w01.w), pkhi(w23.x,w23.y), pkhi(w23.z,w23.w));
                        Al[itl][0] = mk8i(pklo(t01.x,t01.y), pklo(t01.z,t01.w), pklo(t23.x,t23.y), pklo(t23.z,t23.w));
                    }
                    __syncthreads();   // kc=0 reads done before overwrite
                    // ---- pass 1: him for chans 32..63 (ct=2,3) ----
                    #pragma unroll
                    for (int e = 0; e < 4; ++e) {
                        const int row = q * 4 + e;
                        sT1[row][c]      = (unsigned)him[2][e];
                        sT1[row][c + 16] = (unsigned)him[3][e];
                    }
                    __syncthreads();   // stores visible
                    {   // kc = 1 frags
                        const int4 w01 = *(const int4*)&sT1[c][q*8];
                        const int4 w23 = *(const int4*)&sT1[c][q*8 + 4];
                        Ah[itl][1] = mk8i(pklo(w01.x,w01.y), pklo(w01.z,w01.w), pklo(w23.x,w23.y), pklo(w23.z,w23.w));
                        Am[itl][1] = mk8i(pkhi(w01.x,w01.y), pkhi(w01.z,w01.w), pkhi(w23.x,w23.y), pkhi(w23.z,w23.w));
                        Al[itl][1] = mk8i(pkhi(t01.x,t01.y), pkhi(t01.z,t01.w), pkhi(t23.x,t23.y), pkhi(t23.z,t23.w));
                    }
                }

                #pragma unroll
                for (int itl = 0; itl < 2; ++itl)
                    #pragma unroll
                    for (int ct = 0; ct < 4; ++ct) {
                        float b = sB[bo + ct * 16 + c];
                        f32x4 a; a[0]=a[1]=a[2]=a[3]=b; acc[itl][ct]=a;
                    }
                __builtin_amdgcn_s_setprio(1);
                #pragma unroll
                for (int kc = 0; kc < 2; ++kc) {
                    #pragma unroll
                    for (int ct = 0; ct < 4; ++ct) {
                        short8 Bh = ld_frag(fb + (((ct*2+kc)*3 + 0) << 8) + (L << 2));
                        short8 Bm = ld_frag(fb + (((ct*2+kc)*3 + 1) << 8) + (L << 2));
                        short8 Bl = ld_frag(fb + (((ct*2+kc)*3 + 2) << 8) + (L << 2));
                        #pragma unroll
                        for (int itl = 0; itl < 2; ++itl) {
                            acc[itl][ct] = __builtin_amdgcn_mfma_f32_16x16x32_bf16(Ah[itl][kc], Bh, acc[itl][ct], 0,0,0);
                            acc[itl][ct] = __builtin_amdgcn_mfma_f32_16x16x32_bf16(Ah[itl][kc], Bm, acc[itl][ct], 0,0,0);
                            acc[itl][ct] = __builtin_amdgcn_mfma_f32_16x16x32_bf16(Am[itl][kc], Bh, acc[itl][ct], 0,0,0);
                            acc[itl][ct] = __builtin_amdgcn_mfma_f32_16x16x32_bf16(Am[itl][kc], Bm, acc[itl][ct], 0,0,0);
                            acc[itl][ct] = __builtin_amdgcn_mfma_f32_16x16x32_bf16(Ah[itl][kc], Bl, acc[itl][ct], 0,0,0);
                            acc[itl][ct] = __builtin_amdgcn_mfma_f32_16x16x32_bf16(Al[itl][kc], Bh, acc[itl][ct], 0,0,0);
                        }
                    }
                }
                __builtin_amdgcn_s_setprio(0);
            }

            // ---------- heads + dist update (C/D layout) ----------
            {
                float wcr[4], wdr[4];
                #pragma unroll
                for (int ct = 0; ct < 4; ++ct) {
                    wcr[ct] = wf[464 + ct * 16 + c];   // global, L1-resident
                    wdr[ct] = wf[528 + ct * 16 + c];
                }
                #pragma unroll
                for (int e = 0; e < 4; ++e) {
                    const int idx = rt * 16 + q * 4 + e;
                    float d = sDf[idx];
                    #pragma unroll
                    for (int itl = 0; itl < 2; ++itl) {
                        const int it = ip * 2 + itl;
                        float cp = 0.f, dp = 0.f;
                        #pragma unroll
                        for (int ct = 0; ct < 4; ++ct) {
                            float f = fmaxf(acc[itl][ct][e], 0.f);
                            cp = fmaf(f, wcr[ct], cp);
                            dp = fmaf(f, wdr[ct], dp);
                        }
                        cp = rsum16(cp); dp = rsum16(dp);
                        float cls = cp + bcv;
                        float dv  = dp + bdv + sT1m[it][idx];   // masked -> +1e30
                        if (cls > 0.f && dv < d) d = dv;
                    }
                    if (c == 0) sDf[idx] = d;
                }
            }
        }
    }

    __syncthreads();
    float d = sDf[L];
    if (d == INFV) d = 0.f;
    const float hit = (d > 0.f) ? 1.f : 0.f;
    if (fm) {
        ((float*)out_p)[ray]         = hit;
        ((float*)out_p)[NRAYS + ray] = d;
    } else {
        __hip_bfloat16* o = (__hip_bfloat16*)out_p;
        o[ray]         = __float2bfloat16(hit);
        o[NRAYS + ray] = __float2bfloat16(d);
    }
}

extern "C" void kernel_launch(void* const* d_in, const int* in_sizes, int n_in,
                              void* d_out, int out_size, void* d_ws, size_t ws_size,
                              hipStream_t stream) {
    (void)in_sizes; (void)n_in; (void)ws_size; (void)out_size;
    unsigned* ws = (unsigned*)d_ws;
    conv_k<<<1, 256, 0, stream>>>(
        d_in[6], d_in[7], d_in[2],
        d_in[8], d_in[9], d_in[10], d_in[11],
        d_in[12], d_in[13], d_in[14], d_in[15],
        d_in[16], d_in[17], ws);
    nbvh_main<<<NRAYS / 64, 64, 0, stream>>>(
        d_in[0], d_in[1], d_in[2], d_in[4], d_in[5], ws, d_out);
}

// Round 5
// 701.524 us; speedup vs baseline: 1.5364x; 1.0147x over previous
//
#include <hip/hip_runtime.h>
#include <hip/hip_bf16.h>
#include <stdint.h>

#define NRAYS 1048576
#define INFV  1e9f
#define TBIG  1e30f

typedef short short8 __attribute__((ext_vector_type(8)));
typedef float f32x4  __attribute__((ext_vector_type(4)));

// ---- d_ws u32 layout ----
#define WS_B0   16
#define FB0     1024   // L0 frags: 4ct*3h*16lane*4 = 768 u32 (quad0 only)
#define FB1     2048   // L1+L2 frags: 12288 u32

// legacy 2-op packs (prologue only)
#define PKLO(a,b) ((int)(((unsigned)(a) & 0xFFFFu) | ((unsigned)(b) << 16)))
#define PKHI(a,b) ((int)(((unsigned)(a) >> 16) | ((unsigned)(b) & 0xFFFF0000u)))

// single v_perm_b32 packs (main kernel): sel bytes index {S0:S1}, S1=bytes 0-3
__device__ __forceinline__ int pklo(int a, int b) {   // (a&0xFFFF)|(b<<16)
    return (int)__builtin_amdgcn_perm((unsigned)b, (unsigned)a, 0x05040100u);
}
__device__ __forceinline__ int pkhi(int a, int b) {   // (a>>16)|(b&0xFFFF0000)
    return (int)__builtin_amdgcn_perm((unsigned)b, (unsigned)a, 0x07060302u);
}

__device__ __forceinline__ float ldf(const void* p, int i, int fm) {
    if (fm) return ((const float*)p)[i];
    unsigned u = ((const unsigned short*)p)[i];
    return __uint_as_float(u << 16);
}

// bf16x3 split: him = {m_hi16 | h_in_lo16} (1 perm), lo returned RAW
// (low bf16 lives in bytes 2-3; consumers pack pairs with pkhi).
__device__ __forceinline__ void split3(float f, int& him, int& lo_raw) {
    unsigned u = __float_as_uint(f);
    float r = f - __uint_as_float(u & 0xFFFF0000u);
    unsigned um = __float_as_uint(r);
    float r2 = r - __uint_as_float(um & 0xFFFF0000u);
    him    = pkhi((int)u, (int)um);     // (u>>16)|(um&0xFFFF0000)
    lo_raw = (int)__float_as_uint(r2);
}

__device__ __forceinline__ unsigned comp16(int h, float f) {
    unsigned u = __float_as_uint(f);
    if (h == 0) return u >> 16;
    float r = f - __uint_as_float(u & 0xFFFF0000u);
    unsigned um = __float_as_uint(r);
    if (h == 1) return um >> 16;
    float r2 = r - __uint_as_float(um & 0xFFFF0000u);
    return __float_as_uint(r2) >> 16;
}

__device__ __forceinline__ float rsum16(float x) {
    int v;
    v = __builtin_amdgcn_update_dpp(0, __float_as_int(x), 0x128, 0xF, 0xF, false); x += __int_as_float(v);
    v = __builtin_amdgcn_update_dpp(0, __float_as_int(x), 0x124, 0xF, 0xF, false); x += __int_as_float(v);
    v = __builtin_amdgcn_update_dpp(0, __float_as_int(x), 0x122, 0xF, 0xF, false); x += __int_as_float(v);
    v = __builtin_amdgcn_update_dpp(0, __float_as_int(x), 0x121, 0xF, 0xF, false); x += __int_as_float(v);
    return x;
}

union I4S8 { int4 i; short8 s; };
__device__ __forceinline__ short8 mk8i(int a, int b, int c, int d) {
    I4S8 u; u.i = make_int4(a, b, c, d); return u.s;
}
__device__ __forceinline__ short8 ld_frag(const unsigned* p) {
    I4S8 u; u.i = *(const int4*)p; return u.s;
}

// wave-local fence: 1-wave blocks, all LDS traffic wave-private -> lgkmcnt
// drain replaces __syncthreads (validated on HW in the R2 run).
#define WSYNC() asm volatile("s_waitcnt lgkmcnt(0)" ::: "memory")

// ---------------- prologue: now also folds ln_g into Ws frags and
// ln_b@Ws into the layer biases (LN affine removed from main kernel) ----------------
__global__ __launch_bounds__(256) void conv_k(
    const void* __restrict__ mmin, const void* __restrict__ mmax,
    const void* __restrict__ masks,
    const void* __restrict__ W0, const void* __restrict__ b0,
    const void* __restrict__ lng, const void* __restrict__ lnb,
    const void* __restrict__ Ws, const void* __restrict__ bs,
    const void* __restrict__ Wc, const void* __restrict__ bc,
    const void* __restrict__ Wd, const void* __restrict__ bd,
    unsigned* __restrict__ ws)
{
    __shared__ int sfm;
    float* wf = (float*)ws;
    const int tid = threadIdx.x;
    if (tid == 0) {
        unsigned w0 = ((const unsigned*)mmin)[0];
        int fm = ((w0 & 0xFFFFu) == 0u) ? 1 : 0;
        const unsigned* mw = (const unsigned*)masks;
        bool sawBf = false, allBin = true, sawF32 = false;
        for (int i = 0; i < 64; ++i) {
            unsigned w = mw[i], lo = w & 0xFFFFu, hi = w >> 16;
            if (lo == 0x3F80u && (hi == 0x3F80u || hi == 0u)) sawBf = true;
            if (w == 0x3F800000u) sawF32 = true;
            if (w > 1u) allBin = false;
        }
        int ms = sawBf ? 2 : (allBin ? 4 : (sawF32 ? 4 : 1));
        ws[8] = (unsigned)fm; ws[9] = (unsigned)ms;
        for (int c = 0; c < 3; ++c) {
            float mn = ldf(mmin, c, fm), mx = ldf(mmax, c, fm);
            float ext = mx - mn;
            wf[c]     = mn - 0.5f * ext;
            wf[3 + c] = 1.0f / (2.0f * ext);
        }
        wf[6] = ldf(bc, 0, fm);
        wf[7] = ldf(bd, 0, fm);
        sfm = fm;
    }
    __syncthreads();
    const int fm = sfm;

    for (int i = tid; i < 64;  i += 256) { wf[16 + i] = ldf(b0, i, fm); wf[464 + i] = ldf(Wc, i, fm); wf[528 + i] = ldf(Wd, i, fm); }
    // folded layer bias: bs'[li][n] = bs[li][n] + sum_k ln_b[li][k]*Ws[li][k][n]
    for (int i = tid; i < 128; i += 256) {
        int li = i >> 6, n = i & 63;
        float b = ldf(bs, i, fm);
        for (int k = 0; k < 64; ++k)
            b = fmaf(ldf(lnb, li * 64 + k, fm), ldf(Ws, li * 4096 + k * 64 + n, fm), b);
        wf[80 + i] = b;
    }

    for (int w = tid; w < 768; w += 256) {
        int ct = w / 192, rem = w % 192;
        int h = rem / 64, wi = rem % 64;
        int lane16 = wi >> 2, p = wi & 3;
        int n = ct * 16 + lane16;
        unsigned word = 0;
        #pragma unroll
        for (int half = 0; half < 2; ++half) {
            int k = 2 * p + half;
            float v = 0.f;
            if (k < 3) {
                for (int pp = 0; pp < 8; ++pp) v += ldf(W0, (3 * pp + k) * 64 + n, fm);
            } else if (k < 6) {
                int c3 = k - 3;
                for (int pp = 0; pp < 8; ++pp) v = fmaf((float)((double)pp / 7.0), ldf(W0, (3 * pp + c3) * 64 + n, fm), v);
            }
            word |= comp16(h, v) << (16 * half);
        }
        ws[FB0 + ((ct * 3 + h) * 16 + lane16) * 4 + p] = word;
    }

    // layer frags: W' = g_k * W (ln gain folded in, split AFTER the fp32 product)
    for (int w = tid; w < 12288; w += 256) {
        int li = w / 6144, inner = w % 6144;
        int t = inner >> 8;
        int h = t % 3, ckc = t / 3, kc = ckc & 1, ct = ckc >> 1;
        int wi = inner & 255, lane = wi >> 2, p = wi & 3;
        int qq = lane >> 4, cc = lane & 15;
        int n = ct * 16 + cc;
        int k0 = kc * 32 + qq * 8 + 2 * p;
        float g0 = ldf(lng, li * 64 + k0, fm);
        float g1 = ldf(lng, li * 64 + k0 + 1, fm);
        float f0 = g0 * ldf(Ws, li * 4096 + k0 * 64 + n, fm);
        float f1 = g1 * ldf(Ws, li * 4096 + (k0 + 1) * 64 + n, fm);
        ws[FB1 + w] = comp16(h, f0) | (comp16(h, f1) << 16);
    }
}

// ---------------- main: R4 structure + LN-affine fold + WSYNC fences.
// 64 rays/wave, 1-wave blocks, LDS 8960 B (occupancy register-capped at
// 4 waves/SIMD: R2 proved 5/SIMD spills). ----------------
#define ST1_S 34
#define ST2_S 34

__global__ __launch_bounds__(64, 4) void nbvh_main(
    const void* __restrict__ orig_p, const void* __restrict__ vec_p,
    const void* __restrict__ masks_p, const void* __restrict__ t1_p,
    const void* __restrict__ t2_p, const unsigned* __restrict__ wsu,
    void* __restrict__ out_p)
{
    __shared__ __align__(16) unsigned sT1[16][ST1_S];  // 2176 B (one kc half at a time)
    __shared__ __align__(16) unsigned sT2[16][ST2_S];  // 2176 B (lo parts, both kc packed)
    __shared__ float sOV[6][64];    // pre-normalized o',v' (1536 B)
    __shared__ float sT1m[4][64];   // t1 or 1e30 if masked (1024 B)
    __shared__ float sT2g[4][64];   // t2 (1024 B)
    __shared__ float sB[192];       // b0 | bs0' | bs1'  (768 B)
    __shared__ float sDf[64];       // 256 B

    const float* wf = (const float*)wsu;
    const int fm = (int)wsu[8];
    const int ms = (int)wsu[9];
    const float bcv = wf[6], bdv = wf[7];

    const int L = threadIdx.x;
    const int q = L >> 4, c = L & 15;
    const int ray = blockIdx.x * 64 + L;

    for (int i = L; i < 192; i += 64) sB[i] = wf[16 + i];

    {
        const float mn0 = wf[0], mn1 = wf[1], mn2 = wf[2];
        const float is0 = wf[3], is1 = wf[4], is2 = wf[5];
        const float o0 = ldf(orig_p, 3*ray+0, fm), o1 = ldf(orig_p, 3*ray+1, fm), o2 = ldf(orig_p, 3*ray+2, fm);
        const float v0 = ldf(vec_p,  3*ray+0, fm), v1 = ldf(vec_p,  3*ray+1, fm), v2 = ldf(vec_p,  3*ray+2, fm);
        sOV[0][L] = (o0 - mn0) * is0;  sOV[1][L] = (o1 - mn1) * is1;  sOV[2][L] = (o2 - mn2) * is2;
        sOV[3][L] = v0 * is0;          sOV[4][L] = v1 * is1;          sOV[5][L] = v2 * is2;
        #pragma unroll
        for (int it = 0; it < 4; ++it) {
            const int gi = it * NRAYS + ray;
            bool mk;
            if      (ms == 1) mk = ((const uint8_t*) masks_p)[gi] != 0;
            else if (ms == 2) mk = ((const uint16_t*)masks_p)[gi] != 0;
            else              mk = ((const unsigned*) masks_p)[gi] != 0;
            sT1m[it][L] = mk ? ldf(t1_p, gi, fm) : TBIG;   // masked -> dv ~1e30, never selected
            sT2g[it][L] = ldf(t2_p, gi, fm);
        }
        sDf[L] = INFV;
    }
    WSYNC();

    #pragma unroll 1
    for (int rt = 0; rt < 4; ++rt) {
        #pragma unroll 1
        for (int ip = 0; ip < 2; ++ip) {
            f32x4 acc[2][4];
            short8 Ah[2][2], Am[2][2], Al[2][2];   // [itl][kc]

            // ---------- Layer 0: A from recomputed x (k=6 collapsed) ----------
            {
                short8 Xh[2], Xm[2], Xl[2];
                #pragma unroll
                for (int itl = 0; itl < 2; ++itl) {
                    const int it = ip * 2 + itl;
                    const int row = rt * 16 + c;
                    const float t1v = sT1m[it][row];
                    const float dtv = sT2g[it][row] - t1v;
                    float x[6];
                    #pragma unroll
                    for (int j = 0; j < 3; ++j) {
                        float ov = sOV[j][row], vv = sOV[3 + j][row];
                        x[j]     = fmaf(vv, t1v, ov);
                        x[3 + j] = vv * dtv;
                    }
                    int him[6], lo[6];
                    // no q-select on A: B frags are hard zero for q!=0 k-slots,
                    // so garbage A values there multiply 0.
                    #pragma unroll
                    for (int j = 0; j < 6; ++j) split3(x[j], him[j], lo[j]);
                    Xh[itl] = mk8i(pklo(him[0],him[1]), pklo(him[2],him[3]), pklo(him[4],him[5]), 0);
                    Xm[itl] = mk8i(pkhi(him[0],him[1]), pkhi(him[2],him[3]), pkhi(him[4],him[5]), 0);
                    // lo[] raw: low bf16 in bytes 2-3 -> pair-pack via pkhi
                    Xl[itl] = mk8i(pkhi(lo[0], lo[1]),  pkhi(lo[2], lo[3]),  pkhi(lo[4], lo[5]),  0);
                }
                #pragma unroll
                for (int itl = 0; itl < 2; ++itl)
                    #pragma unroll
                    for (int ct = 0; ct < 4; ++ct) {
                        float b = sB[ct * 16 + c];
                        f32x4 a; a[0]=a[1]=a[2]=a[3]=b; acc[itl][ct]=a;
                    }
                __builtin_amdgcn_s_setprio(1);
                #pragma unroll
                for (int ct = 0; ct < 4; ++ct) {
                    short8 Bh = (q==0) ? ld_frag(wsu + FB0 + ((ct*3+0)*16 + c)*4) : mk8i(0,0,0,0);
                    short8 Bm = (q==0) ? ld_frag(wsu + FB0 + ((ct*3+1)*16 + c)*4) : mk8i(0,0,0,0);
                    short8 Bl = (q==0) ? ld_frag(wsu + FB0 + ((ct*3+2)*16 + c)*4) : mk8i(0,0,0,0);
                    #pragma unroll
                    for (int itl = 0; itl < 2; ++itl) {
                        acc[itl][ct] = __builtin_amdgcn_mfma_f32_16x16x32_bf16(Xh[itl], Bh, acc[itl][ct], 0,0,0);
                        acc[itl][ct] = __builtin_amdgcn_mfma_f32_16x16x32_bf16(Xh[itl], Bm, acc[itl][ct], 0,0,0);
                        acc[itl][ct] = __builtin_amdgcn_mfma_f32_16x16x32_bf16(Xm[itl], Bh, acc[itl][ct], 0,0,0);
                        acc[itl][ct] = __builtin_amdgcn_mfma_f32_16x16x32_bf16(Xm[itl], Bm, acc[itl][ct], 0,0,0);
                        acc[itl][ct] = __builtin_amdgcn_mfma_f32_16x16x32_bf16(Xh[itl], Bl, acc[itl][ct], 0,0,0);
                        acc[itl][ct] = __builtin_amdgcn_mfma_f32_16x16x32_bf16(Xl[itl], Bh, acc[itl][ct], 0,0,0);
                    }
                }
                __builtin_amdgcn_s_setprio(0);
            }

            // ---------- layers: LN(stats only) -> half-pass stage -> build A; matmul ----------
            #pragma unroll 1
            for (int layer = 0; layer < 2; ++layer) {
                const unsigned* fb = wsu + FB1 + layer * 6144;
                const int bo = 64 + layer * 64;

                #pragma unroll
                for (int itl = 0; itl < 2; ++itl) {
                    WSYNC();   // previous itl's A-build reads done
                    float z[4][4];
                    #pragma unroll
                    for (int ct = 0; ct < 4; ++ct)
                        #pragma unroll
                        for (int e = 0; e < 4; ++e) z[ct][e] = fmaxf(acc[itl][ct][e], 0.f);
                    float mu[4], rs[4];
                    #pragma unroll
                    for (int e = 0; e < 4; ++e) {
                        float s  = z[0][e] + z[1][e] + z[2][e] + z[3][e];
                        float s2 = fmaf(z[0][e], z[0][e], fmaf(z[1][e], z[1][e],
                                   fmaf(z[2][e], z[2][e], z[3][e] * z[3][e])));
                        s  = rsum16(s);    // two independent DPP chains interleave
                        s2 = rsum16(s2);
                        mu[e] = s * (1.0f / 64.0f);
                        float var = fmaf(-mu[e], mu[e], s2 * (1.0f / 64.0f));
                        rs[e] = rsqrtf(var + 1e-5f);
                    }
                    int him[4][4], lov[4][4];
                    #pragma unroll
                    for (int ct = 0; ct < 4; ++ct) {
                        #pragma unroll
                        for (int e = 0; e < 4; ++e) {
                            float y = (z[ct][e] - mu[e]) * rs[e];   // g,h folded into W',b'
                            split3(y, him[ct][e], lov[ct][e]);
                        }
                    }
                    // ---- pass 0: him for chans 0..31 (ct=0,1) + all lo parts ----
                    #pragma unroll
                    for (int e = 0; e < 4; ++e) {
                        const int row = q * 4 + e;
                        sT1[row][c]      = (unsigned)him[0][e];
                        sT1[row][c + 16] = (unsigned)him[1][e];
                        // lov raw: pair-pack low bf16s via pkhi
                        sT2[row][c]      = (unsigned)pkhi(lov[0][e], lov[2][e]);
                        sT2[row][c + 16] = (unsigned)pkhi(lov[1][e], lov[3][e]);
                    }
                    WSYNC();   // stores visible (wave-local)
                    const int4 t01 = *(const int4*)&sT2[c][q*8];
                    const int4 t23 = *(const int4*)&sT2[c][q*8 + 4];
                    {   // kc = 0 frags
                        const int4 w01 = *(const int4*)&sT1[c][q*8];
                        const int4 w23 = *(const int4*)&sT1[c][q*8 + 4];
                        Ah[itl][0] = mk8i(pklo(w01.x,w01.y), pklo(w01.z,w01.w), pklo(w23.x,w23.y), pklo(w23.z,w23.w));
                        Am[itl][0] = mk8i(pkhi(w01.x,w01.y), pkhi(w01.z,w01.w), pkhi(w23.x,w23.y), pkhi(w23.z,w23.w));
                        Al[itl][0] = mk8i(pklo(t01.x,t01.y), pklo(t01.z,t01.w), pklo(t23.x,t23.y), pklo(t23.z,t23.w));
                    }
                    WSYNC();   // kc=0 reads done before overwrite
                    // ---- pass 1: him for chans 32..63 (ct=2,3) ----
                    #pragma unroll
                    for (int e = 0; e < 4; ++e) {
                        const int row = q * 4 + e;
                        sT1[row][c]      = (unsigned)him[2][e];
                        sT1[row][c + 16] = (unsigned)him[3][e];
                    }
                    WSYNC();   // stores visible
                    {   // kc = 1 frags
                        const int4 w01 = *(const int4*)&sT1[c][q*8];
                        const int4 w23 = *(const int4*)&sT1[c][q*8 + 4];
                        Ah[itl][1] = mk8i(pklo(w01.x,w01.y), pklo(w01.z,w01.w), pklo(w23.x,w23.y), pklo(w23.z,w23.w));
                        Am[itl][1] = mk8i(pkhi(w01.x,w01.y), pkhi(w01.z,w01.w), pkhi(w23.x,w23.y), pkhi(w23.z,w23.w));
                        Al[itl][1] = mk8i(pkhi(t01.x,t01.y), pkhi(t01.z,t01.w), pkhi(t23.x,t23.y), pkhi(t23.z,t23.w));
                    }
                }

                #pragma unroll
                for (int itl = 0; itl < 2; ++itl)
                    #pragma unroll
                    for (int ct = 0; ct < 4; ++ct) {
                        float b = sB[bo + ct * 16 + c];
                        f32x4 a; a[0]=a[1]=a[2]=a[3]=b; acc[itl][ct]=a;
                    }
                __builtin_amdgcn_s_setprio(1);
                #pragma unroll
                for (int kc = 0; kc < 2; ++kc) {
                    #pragma unroll
                    for (int ct = 0; ct < 4; ++ct) {
                        short8 Bh = ld_frag(fb + (((ct*2+kc)*3 + 0) << 8) + (L << 2));
                        short8 Bm = ld_frag(fb + (((ct*2+kc)*3 + 1) << 8) + (L << 2));
                        short8 Bl = ld_frag(fb + (((ct*2+kc)*3 + 2) << 8) + (L << 2));
                        #pragma unroll
                        for (int itl = 0; itl < 2; ++itl) {
                            acc[itl][ct] = __builtin_amdgcn_mfma_f32_16x16x32_bf16(Ah[itl][kc], Bh, acc[itl][ct], 0,0,0);
                            acc[itl][ct] = __builtin_amdgcn_mfma_f32_16x16x32_bf16(Ah[itl][kc], Bm, acc[itl][ct], 0,0,0);
                            acc[itl][ct] = __builtin_amdgcn_mfma_f32_16x16x32_bf16(Am[itl][kc], Bh, acc[itl][ct], 0,0,0);
                            acc[itl][ct] = __builtin_amdgcn_mfma_f32_16x16x32_bf16(Am[itl][kc], Bm, acc[itl][ct], 0,0,0);
                            acc[itl][ct] = __builtin_amdgcn_mfma_f32_16x16x32_bf16(Ah[itl][kc], Bl, acc[itl][ct], 0,0,0);
                            acc[itl][ct] = __builtin_amdgcn_mfma_f32_16x16x32_bf16(Al[itl][kc], Bh, acc[itl][ct], 0,0,0);
                        }
                    }
                }
                __builtin_amdgcn_s_setprio(0);
            }

            // ---------- heads + dist update (C/D layout) ----------
            {
                float wcr[4], wdr[4];
                #pragma unroll
                for (int ct = 0; ct < 4; ++ct) {
                    wcr[ct] = wf[464 + ct * 16 + c];   // global, L1-resident
                    wdr[ct] = wf[528 + ct * 16 + c];
                }
                #pragma unroll
                for (int e = 0; e < 4; ++e) {
                    const int idx = rt * 16 + q * 4 + e;
                    float d = sDf[idx];
                    #pragma unroll
                    for (int itl = 0; itl < 2; ++itl) {
                        const int it = ip * 2 + itl;
                        float cp = 0.f, dp = 0.f;
                        #pragma unroll
                        for (int ct = 0; ct < 4; ++ct) {
                            float f = fmaxf(acc[itl][ct][e], 0.f);
                            cp = fmaf(f, wcr[ct], cp);
                            dp = fmaf(f, wdr[ct], dp);
                        }
                        cp = rsum16(cp); dp = rsum16(dp);
                        float cls = cp + bcv;
                        float dv  = dp + bdv + sT1m[it][idx];   // masked -> +1e30
                        if (cls > 0.f && dv < d) d = dv;
                    }
                    if (c == 0) sDf[idx] = d;
                }
            }
        }
    }

    WSYNC();
    float d = sDf[L];
    if (d == INFV) d = 0.f;
    const float hit = (d > 0.f) ? 1.f : 0.f;
    if (fm) {
        ((float*)out_p)[ray]         = hit;
        ((float*)out_p)[NRAYS + ray] = d;
    } else {
        __hip_bfloat16* o = (__hip_bfloat16*)out_p;
        o[ray]         = __float2bfloat16(hit);
        o[NRAYS + ray] = __float2bfloat16(d);
    }
}

extern "C" void kernel_launch(void* const* d_in, const int* in_sizes, int n_in,
                              void* d_out, int out_size, void* d_ws, size_t ws_size,
                              hipStream_t stream) {
    (void)in_sizes; (void)n_in; (void)ws_size; (void)out_size;
    unsigned* ws = (unsigned*)d_ws;
    conv_k<<<1, 256, 0, stream>>>(
        d_in[6], d_in[7], d_in[2],
        d_in[8], d_in[9], d_in[10], d_in[11],
        d_in[12], d_in[13], d_in[14], d_in[15],
        d_in[16], d_in[17], ws);
    nbvh_main<<<NRAYS / 64, 64, 0, stream>>>(
        d_in[0], d_in[1], d_in[2], d_in[4], d_in[5], ws, d_out);
}